// Round 7
// baseline (196.843 us; speedup 1.0000x reference)
//
#include <hip/hip_runtime.h>

#define SEQ    512
#define BATCH  1024
#define NTAG   54
#define TSTART 52
#define TSTOP  53
#define NW     4   // waves (batch elements) per block

// ---------------------------------------------------------------------------
// Linear-space CRF forward. wave = batch element, lane = tag j.
//
//   u[j] = exp(alpha[j] - esum*ln2)
//   step: u' = (sum_i Elin[j,i]*u[i]) * (exp(feat[j]) * 2^-e_lag)
//   Elin[j,i] = exp(trans[j,i])  (56 VGPRs/lane incl. zero pad, constant)
//   e_lag = exponent of readlane(u,0) from previous step (off-chain)
//   exp(feat) applied at use; raw floats prefetched 8 steps deep.
//
// Round-7 change: broadcast u via LDS (1 ds_write_b32 + 14 broadcast
// ds_read_b128, conflict-free, in-order same-wave DS pipe) instead of 54
// v_readlane->SGPR->v_fma pairs. Rounds 4-6 plateaued at 956 cyc/step with
// ~258 VALU instr/step: readlane carries VALU->SGPR->VALU hazards and the
// compiler (SGPR_Count=48) can't pre-schedule 54 SGPR results; Elin was not
// arch-VGPR-resident (VGPR_Count=56). The LDS path uses VGPR-only FMA
// operands and a separate pipe. Elin pinned with in-loop opaque asm.
// ---------------------------------------------------------------------------

#define MATVEC_STEP(FV, MK) do {                                              \
    alds[wv][lane] = u;                                                       \
    float efs_ = __expf(FV) * __uint_as_float((unsigned)(127 - e_lag) << 23); \
    float a0_ = 0.f, a1_ = 0.f, a2_ = 0.f, a3_ = 0.f;                         \
    const float4* ap_ = (const float4*)(&alds[wv][0]);                        \
    _Pragma("unroll")                                                         \
    for (int g_ = 0; g_ < 14; ++g_) {                                         \
        float4 av_ = ap_[g_];                                                 \
        a0_ = fmaf(Elin[4*g_+0], av_.x, a0_);                                 \
        a1_ = fmaf(Elin[4*g_+1], av_.y, a1_);                                 \
        a2_ = fmaf(Elin[4*g_+2], av_.z, a2_);                                 \
        a3_ = fmaf(Elin[4*g_+3], av_.w, a3_);                                 \
    }                                                                         \
    float w_  = (a0_ + a1_) + (a2_ + a3_);                                    \
    float un_ = w_ * efs_;                                                    \
    bool  up_ = (MK) > 0;                                                     \
    u = up_ ? un_ : u;                                                        \
    esum += up_ ? e_lag : 0;                                                  \
    unsigned ub_ = (unsigned)__builtin_amdgcn_readlane(__float_as_int(u), 0); \
    int en_ = (int)((ub_ >> 23) & 255u) - 127;                                \
    e_lag = en_ < -40 ? -40 : (en_ > 40 ? 40 : en_);                          \
} while (0)

__global__ __launch_bounds__(64 * NW, 1) void crf_fwd_kernel(
    const float* __restrict__ em, const float* __restrict__ tr,
    const int* __restrict__ tags, const int* __restrict__ mask,
    float* __restrict__ part, int* __restrict__ msum)
{
    __shared__ float tlds[NTAG * NTAG];
    __shared__ __align__(16) float alds[NW][64];

    const int tid = threadIdx.x;
    for (int k = tid; k < NTAG * NTAG; k += 64 * NW) tlds[k] = tr[k];
    __syncthreads();

    const int wv   = tid >> 6;
    const int lane = tid & 63;
    const int b    = blockIdx.x * NW + wv;
    const size_t bT = (size_t)b * NTAG;

    // --- Elin = exp(trans) rows (padded to 56 with zeros), register-resident
    float Elin[56];
    #pragma unroll
    for (int i = 0; i < 56; ++i) {
        Elin[i] = (lane < NTAG && i < NTAG) ? __expf(tlds[lane * NTAG + i]) : 0.f;
        asm volatile("" : "+v"(Elin[i]));   // no remat / no sink
    }
    float estop = (lane < NTAG) ? __expf(tlds[TSTOP * NTAG + lane]) : 0.f;

    // =======================================================================
    // Gold prepass: time-parallel (lane l handles steps l, l+64, ..., l+448)
    // =======================================================================
    float goldp = 0.f;
    int   msump = 0;
    #pragma unroll
    for (int r = 0; r < 8; ++r) {
        int s  = r * 64 + lane;
        int tg = tags[s * BATCH + b];
        int mk = mask[s * BATCH + b];
        int tp = (s == 0) ? TSTART : tags[(s - 1) * BATCH + b];
        float emv = em[(size_t)s * (BATCH * NTAG) + bT + tg];
        float trv = tlds[tg * NTAG + tp];
        float mf  = (s == 0) ? 1.f : (float)mk;
        goldp = fmaf(trv + emv, mf, goldp);
        msump += mk;
    }
    #pragma unroll
    for (int off = 32; off >= 1; off >>= 1) {
        goldp += __shfl_xor(goldp, off);
        msump += __shfl_xor(msump, off);
    }

    // =======================================================================
    // Serial forward recursion (LDS broadcast matvec, raw prefetch)
    // =======================================================================
    float u     = (lane == TSTART) ? 1.f : 0.f;
    int   esum  = 0;
    int   e_lag = 0;

    #define LDF(S) ((lane < NTAG) ? em[(size_t)(S) * (BATCH * NTAG) + bT + lane] : 0.f)
    #define LDM(S) (mask[(S) * BATCH + b])

    float F0 = LDF(0), F1 = LDF(1), F2 = LDF(2), F3 = LDF(3);
    float F4 = LDF(4), F5 = LDF(5), F6 = LDF(6), F7 = LDF(7);
    int   k0 = LDM(0), k1 = LDM(1), k2 = LDM(2), k3 = LDM(3);
    int   k4 = LDM(4), k5 = LDM(5), k6 = LDM(6), k7 = LDM(7);

    for (int sb = 0; sb < SEQ; sb += 8) {
        #pragma unroll
        for (int i = 0; i < 56; ++i) asm volatile("" : "+v"(Elin[i]));  // keep live
        MATVEC_STEP(F0, k0);
        { int sn = (sb +  8 < SEQ) ? sb +  8 : SEQ - 1; F0 = LDF(sn); k0 = LDM(sn); }
        MATVEC_STEP(F1, k1);
        { int sn = (sb +  9 < SEQ) ? sb +  9 : SEQ - 1; F1 = LDF(sn); k1 = LDM(sn); }
        MATVEC_STEP(F2, k2);
        { int sn = (sb + 10 < SEQ) ? sb + 10 : SEQ - 1; F2 = LDF(sn); k2 = LDM(sn); }
        MATVEC_STEP(F3, k3);
        { int sn = (sb + 11 < SEQ) ? sb + 11 : SEQ - 1; F3 = LDF(sn); k3 = LDM(sn); }
        MATVEC_STEP(F4, k4);
        { int sn = (sb + 12 < SEQ) ? sb + 12 : SEQ - 1; F4 = LDF(sn); k4 = LDM(sn); }
        MATVEC_STEP(F5, k5);
        { int sn = (sb + 13 < SEQ) ? sb + 13 : SEQ - 1; F5 = LDF(sn); k5 = LDM(sn); }
        MATVEC_STEP(F6, k6);
        { int sn = (sb + 14 < SEQ) ? sb + 14 : SEQ - 1; F6 = LDF(sn); k6 = LDM(sn); }
        MATVEC_STEP(F7, k7);
        { int sn = (sb + 15 < SEQ) ? sb + 15 : SEQ - 1; F7 = LDF(sn); k7 = LDM(sn); }
    }

    // --- final forward score: log(sum_j u[j]*exp(trans[STOP,j])) + esum*ln2 ---
    float us = u * estop;
    #pragma unroll
    for (int off = 32; off >= 1; off >>= 1) us += __shfl_xor(us, off);
    float fwd = __logf(us) + (float)esum * 0.69314718f;

    // --- gold: stop transition from tags[length-1] ---
    int li   = (msump > 0) ? (msump - 1) : 0;
    int ltag = tags[li * BATCH + b];
    float gold = goldp + tlds[TSTOP * NTAG + ltag];

    if (lane == 0) { part[b] = fwd - gold; msum[b] = msump; }
    #undef LDF
    #undef LDM
}

// ---------------------------------------------------------------------------
// Kernel 2: deterministic reduction  out = sum(part) / sum(msum)
// ---------------------------------------------------------------------------
__global__ __launch_bounds__(256) void crf_reduce_kernel(
    const float* __restrict__ part, const int* __restrict__ msum,
    float* __restrict__ out)
{
    const int tid = threadIdx.x;
    float s = 0.f;
    int   m = 0;
    for (int k = tid; k < BATCH; k += 256) { s += part[k]; m += msum[k]; }
    #pragma unroll
    for (int off = 32; off >= 1; off >>= 1) {
        s += __shfl_xor(s, off);
        m += __shfl_xor(m, off);
    }
    __shared__ float sl[4];
    __shared__ int   ml[4];
    if ((tid & 63) == 0) { sl[tid >> 6] = s; ml[tid >> 6] = m; }
    __syncthreads();
    if (tid == 0)
        out[0] = (sl[0] + sl[1] + sl[2] + sl[3]) /
                 (float)(ml[0] + ml[1] + ml[2] + ml[3]);
}

extern "C" void kernel_launch(void* const* d_in, const int* in_sizes, int n_in,
                              void* d_out, int out_size, void* d_ws, size_t ws_size,
                              hipStream_t stream)
{
    const float* em   = (const float*)d_in[0];
    const float* tr   = (const float*)d_in[1];
    const int*   tags = (const int*)d_in[2];
    const int*   mask = (const int*)d_in[3];

    float* part  = (float*)d_ws;
    int*   msumw = (int*)((char*)d_ws + BATCH * sizeof(float));
    float* out   = (float*)d_out;

    crf_fwd_kernel<<<BATCH / NW, 64 * NW, 0, stream>>>(em, tr, tags, mask, part, msumw);
    crf_reduce_kernel<<<1, 256, 0, stream>>>(part, msumw, out);
}

// Round 8
// 167.371 us; speedup vs baseline: 1.1761x; 1.1761x over previous
//
#include <hip/hip_runtime.h>
#include <stdint.h>

#define SEQ    512
#define BATCH  1024
#define NTAG   54
#define TSTART 52
#define TSTOP  53
#define NW     4
#define EMROW  (BATCH * NTAG)   // 55296 floats per timestep

// ---------------------------------------------------------------------------
// Linear-space CRF forward. wave = batch element, lane = tag j.
//   u[j] = exp(alpha[j] - esum*ln2)
//   step: u' = (sum_i Elin[j,i]*u[i]) * (exp(feat[j]) * 2^-e_lag)
//
// Round-8 change: emissions staged via global_load_lds into a 16-slot LDS
// ring, 8 steps ahead, counted s_waitcnt vmcnt(8) per step (never 0). The
// prefetch no longer occupies VGPRs, so the compiler cannot sink the loads
// (rounds 4-7 plateaued at ~1000 cyc/step = exposed HBM latency; its
// pressure heuristic refused 16 live load results). Masks are prepassed
// into 8 ballot words -> zero in-loop mask loads; in-loop VMEM = exactly
// one stage op per step, so the manual vmcnt count is exact.
// ---------------------------------------------------------------------------

typedef const __attribute__((address_space(1))) void* gld_gptr;
typedef __attribute__((address_space(3))) void*       gld_lptr;

__device__ __forceinline__ void stage4(const float* g, float* l) {
    __builtin_amdgcn_global_load_lds((gld_gptr)g, (gld_lptr)l, 4, 0, 0);
}

#define STEP(o, INC) do {                                                     \
    stage4(gp, (float*)&flds[wv][((o) + 8) & 15][0]);                         \
    gp += (INC);                                                              \
    asm volatile("s_waitcnt vmcnt(8)" ::: "memory");                          \
    float fv_ = flds[wv][(o)][lane];                                          \
    alds[wv][lane] = u;                                                       \
    float efs_ = __expf(fv_) * __uint_as_float((unsigned)(127 - e_lag) << 23);\
    float a0_ = 0.f, a1_ = 0.f, a2_ = 0.f, a3_ = 0.f;                         \
    const float4* ap_ = (const float4*)(&alds[wv][0]);                        \
    _Pragma("unroll")                                                         \
    for (int g_ = 0; g_ < 14; ++g_) {                                         \
        float4 av_ = ap_[g_];                                                 \
        a0_ = fmaf(Elin[4*g_+0], av_.x, a0_);                                 \
        a1_ = fmaf(Elin[4*g_+1], av_.y, a1_);                                 \
        a2_ = fmaf(Elin[4*g_+2], av_.z, a2_);                                 \
        a3_ = fmaf(Elin[4*g_+3], av_.w, a3_);                                 \
    }                                                                         \
    float w_  = (a0_ + a1_) + (a2_ + a3_);                                    \
    float un_ = w_ * efs_;                                                    \
    bool  up_ = (cur & 1ull) != 0ull;                                         \
    cur >>= 1;                                                                \
    u = up_ ? un_ : u;                                                        \
    esum += up_ ? e_lag : 0;                                                  \
    unsigned ub_ = (unsigned)__builtin_amdgcn_readlane(__float_as_int(u), 0); \
    int en_ = (int)((ub_ >> 23) & 255u) - 127;                                \
    e_lag = en_ < -40 ? -40 : (en_ > 40 ? 40 : en_);                          \
} while (0)

__global__ __launch_bounds__(64 * NW, 1) void crf_fwd_kernel(
    const float* __restrict__ em, const float* __restrict__ tr,
    const int* __restrict__ tags, const int* __restrict__ mask,
    float* __restrict__ part, int* __restrict__ msum)
{
    __shared__ float tlds[NTAG * NTAG];
    __shared__ __align__(16) float alds[NW][64];
    __shared__ __align__(16) float flds[NW][16][64];   // emission staging ring

    const int tid = threadIdx.x;
    for (int k = tid; k < NTAG * NTAG; k += 64 * NW) tlds[k] = tr[k];
    __syncthreads();

    const int wv   = tid >> 6;
    const int lane = tid & 63;
    const int b    = blockIdx.x * NW + wv;
    const size_t bT = (size_t)b * NTAG;

    // --- Elin = exp(trans) rows (zero-padded to 56) ---
    float Elin[56];
    #pragma unroll
    for (int i = 0; i < 56; ++i) {
        Elin[i] = (lane < NTAG && i < NTAG) ? __expf(tlds[lane * NTAG + i]) : 0.f;
        asm("" : "+v"(Elin[i]));
    }
    float estop = (lane < NTAG) ? __expf(tlds[TSTOP * NTAG + lane]) : 0.f;

    // =======================================================================
    // Prepass: gold path + mask ballots (lane l handles steps l, l+64, ...)
    // =======================================================================
    float    goldp = 0.f;
    int      msump = 0;
    uint64_t B[8];
    #pragma unroll
    for (int r = 0; r < 8; ++r) {
        int s  = r * 64 + lane;
        int tg = tags[s * BATCH + b];
        int mk = mask[s * BATCH + b];
        int tp = (s == 0) ? TSTART : tags[(s - 1) * BATCH + b];
        float emv = em[(size_t)s * EMROW + bT + tg];
        float trv = tlds[tg * NTAG + tp];
        float mf  = (s == 0) ? 1.f : (float)mk;
        goldp = fmaf(trv + emv, mf, goldp);
        msump += mk;
        B[r] = __ballot(mk > 0);
    }
    #pragma unroll
    for (int off = 32; off >= 1; off >>= 1) {
        goldp += __shfl_xor(goldp, off);
        msump += __shfl_xor(msump, off);
    }

    // =======================================================================
    // Serial forward recursion
    // =======================================================================
    float u     = (lane == TSTART) ? 1.f : 0.f;
    int   esum  = 0;
    int   e_lag = 0;

    // drain prepass VMEM so the staging vmcnt count is exact
    asm volatile("s_waitcnt vmcnt(0)" ::: "memory");

    const float* gp = em + bT + (lane < NTAG ? lane : NTAG - 1);
    #pragma unroll
    for (int s = 0; s < 8; ++s) {          // prologue: stage steps 0..7
        stage4(gp, (float*)&flds[wv][s][0]);
        gp += EMROW;
    }                                       // gp -> stage step 8

    for (int c = 0; c < 8; ++c) {
        uint64_t cur = B[0];
        for (int q = 0; q < 4; ++q) {
            const size_t incB = (c == 7 && q == 3) ? 0 : (size_t)EMROW;
            STEP( 0, EMROW); STEP( 1, EMROW); STEP( 2, EMROW); STEP( 3, EMROW);
            STEP( 4, EMROW); STEP( 5, EMROW); STEP( 6, EMROW); STEP( 7, incB);
            STEP( 8, incB);  STEP( 9, incB);  STEP(10, incB);  STEP(11, incB);
            STEP(12, incB);  STEP(13, incB);  STEP(14, incB);  STEP(15, incB);
        }
        #pragma unroll
        for (int r = 0; r < 7; ++r) B[r] = B[r + 1];
    }

    // --- final forward score: log(sum_j u[j]*exp(trans[STOP,j])) + esum*ln2 ---
    float us = u * estop;
    #pragma unroll
    for (int off = 32; off >= 1; off >>= 1) us += __shfl_xor(us, off);
    float fwd = __logf(us) + (float)esum * 0.69314718f;

    // --- gold: stop transition from tags[length-1] ---
    asm volatile("s_waitcnt vmcnt(0)" ::: "memory");   // clean counter state
    int li   = (msump > 0) ? (msump - 1) : 0;
    int ltag = tags[li * BATCH + b];
    float gold = goldp + tlds[TSTOP * NTAG + ltag];

    if (lane == 0) { part[b] = fwd - gold; msum[b] = msump; }
}

// ---------------------------------------------------------------------------
// Kernel 2: deterministic reduction  out = sum(part) / sum(msum)
// ---------------------------------------------------------------------------
__global__ __launch_bounds__(256) void crf_reduce_kernel(
    const float* __restrict__ part, const int* __restrict__ msum,
    float* __restrict__ out)
{
    const int tid = threadIdx.x;
    float s = 0.f;
    int   m = 0;
    for (int k = tid; k < BATCH; k += 256) { s += part[k]; m += msum[k]; }
    #pragma unroll
    for (int off = 32; off >= 1; off >>= 1) {
        s += __shfl_xor(s, off);
        m += __shfl_xor(m, off);
    }
    __shared__ float sl[4];
    __shared__ int   ml[4];
    if ((tid & 63) == 0) { sl[tid >> 6] = s; ml[tid >> 6] = m; }
    __syncthreads();
    if (tid == 0)
        out[0] = (sl[0] + sl[1] + sl[2] + sl[3]) /
                 (float)(ml[0] + ml[1] + ml[2] + ml[3]);
}

extern "C" void kernel_launch(void* const* d_in, const int* in_sizes, int n_in,
                              void* d_out, int out_size, void* d_ws, size_t ws_size,
                              hipStream_t stream)
{
    const float* em   = (const float*)d_in[0];
    const float* tr   = (const float*)d_in[1];
    const int*   tags = (const int*)d_in[2];
    const int*   mask = (const int*)d_in[3];

    float* part  = (float*)d_ws;
    int*   msumw = (int*)((char*)d_ws + BATCH * sizeof(float));
    float* out   = (float*)d_out;

    crf_fwd_kernel<<<BATCH / NW, 64 * NW, 0, stream>>>(em, tr, tags, mask, part, msumw);
    crf_reduce_kernel<<<1, 256, 0, stream>>>(part, msumw, out);
}